// Round 10
// baseline (216.264 us; speedup 1.0000x reference)
//
#include <hip/hip_runtime.h>

// SelfAttention: B=4, S=4096, E=1024, H=64, single head, causal, p=0.
// I/O fp32, internals bf16 MFMA.
// Round 10: attn blocks grow to 256 thr / 128 Q-rows (4 waves x 32 rows):
// halves tile-visits, barriers, and K/V staging traffic vs R7's 64-row tiles.
// Split-K chunks of 8 kt over 32 q-tiles (144 chunks/batch, 576 blocks).
// Proj (R9 contiguous-DMA) and transpose unchanged.

using short8 = __attribute__((ext_vector_type(8))) short;
using f32x4  = __attribute__((ext_vector_type(4))) float;

#define MFMA16(A, B, C) __builtin_amdgcn_mfma_f32_16x16x32_bf16((A), (B), (C), 0, 0, 0)

typedef const __attribute__((address_space(1))) void* gas_ptr;
typedef __attribute__((address_space(3))) void*       las_ptr;

__device__ __forceinline__ void gload16(const void* g, void* l) {
    // async global->LDS, 16B/lane, LDS dst = base + lane*16 (wave-uniform base)
    __builtin_amdgcn_global_load_lds((gas_ptr)g, (las_ptr)l, 16, 0, 0);
}

__device__ __forceinline__ unsigned short f2bf(float f) {
    unsigned u = __builtin_bit_cast(unsigned, f);
    u += 0x7fffu + ((u >> 16) & 1u);   // RNE
    return (unsigned short)(u >> 16);
}
__device__ __forceinline__ float bf2f(unsigned short u) {
    unsigned v = ((unsigned)u) << 16;
    return __builtin_bit_cast(float, v);
}

// ------------------------------------------------- W frag-order pack + Vt pad
__global__ __launch_bounds__(256) void transpose_w(
    const float* __restrict__ Wq,
    const float* __restrict__ Wk,
    const float* __restrict__ Wv,
    unsigned short* __restrict__ Ws,
    unsigned short* __restrict__ Vt)
{
    int o = blockIdx.x * 256 + threadIdx.x;   // 196608 + 262144 total
    if (o < 196608) {
        int j    = o & 7;
        int l    = (o >> 3) & 63;
        int g    = (o >> 9) & 7;
        int rem  = o >> 12;        // sk*3 + mt
        int mt   = rem % 3;
        int sk   = rem / 3;
        int c    = g >> 2, nt = g & 3;
        int quad = l >> 4, n  = l & 15;
        int e    = sk * 64 + c * 32 + quad * 8 + j;
        int h    = nt * 16 + n;
        const float* W = (mt == 0) ? Wq : (mt == 1) ? Wk : Wv;
        Ws[o] = f2bf(W[e * 64 + h]);
    } else {
        int jj  = o - 196608;                 // 4 b x 16 rows x 4096
        int b   = jj >> 16;
        int rem = jj & 65535;
        int h   = 64 + (rem >> 12);
        int s   = rem & 4095;
        Vt[((size_t)(b * 80 + h)) * 4096 + s] = (h == 64) ? 0x3F80 : 0;
    }
}

// ---------------------------------------------------------------- projection
// (R9 structure, unchanged) 512 blocks x 2 waves, 32 rows x 192 cols,
// double-buffered contiguous-DMA staging.
__global__ __launch_bounds__(128, 2) void proj_all(
    const float* __restrict__ x,             // [16384][1024] fp32
    const unsigned short* __restrict__ Ws,   // [16][3][8][64][8] bf16 frag-order
    unsigned short* __restrict__ Qo,         // [16384][64] bf16
    unsigned short* __restrict__ Ko,         // [16384][64] bf16
    unsigned short* __restrict__ Vto)        // [4][80][4096] bf16 (V^T, padded)
{
    const int m0   = blockIdx.x * 32;
    const int tid  = threadIdx.x;
    const int lane = tid & 63;
    const int wv   = tid >> 6;     // 0..1
    const int quad = lane >> 4;
    const int n    = lane & 15;

    __shared__ __align__(16) float xs[2][8][64][4];   // 16 KB
    __shared__ __align__(16) short wf[2][24][64][8];  // 48 KB

    const f32x4 zero4 = {0.f, 0.f, 0.f, 0.f};
    f32x4 acc[3][4];
    #pragma unroll
    for (int mt = 0; mt < 3; ++mt)
        #pragma unroll
        for (int nt = 0; nt < 4; ++nt) acc[mt][nt] = zero4;

    auto stage = [&](int k0, int p) {
        #pragma unroll
        for (int it = 0; it < 4; ++it) {
            int i     = wv + 2 * it;                 // 0..7
            int Rl    = 4 * i + (lane >> 4);         // local row 0..31
            int chunk = (lane & 15) ^ ((Rl & 3) << 2);
            gload16(x + (size_t)(m0 + Rl) * 1024 + k0 + chunk * 4, &xs[p][i][0][0]);
        }
        int sk = k0 >> 6;
        #pragma unroll
        for (int it = 0; it < 12; ++it) {
            int f = wv + 2 * it;                     // 0..23
            gload16(Ws + (((size_t)sk * 24 + f) << 9) + lane * 8, &wf[p][f][0][0]);
        }
    };

    int p = 0;
    stage(0, 0);
    __syncthreads();

    for (int k0 = 0; k0 < 1024; k0 += 64) {
        if (k0 < 960) stage(k0 + 64, p ^ 1);   // prefetch (drained at barrier)

        int sub = n & 3, s = sub << 2;
        const float* xp = &xs[p][wv * 4 + (n >> 2)][0][0] + sub * 64;
        f32x4 u0 = *(const f32x4*)(xp + (((2 * quad)     ^ s) << 2));
        f32x4 u1 = *(const f32x4*)(xp + (((2 * quad + 1) ^ s) << 2));
        f32x4 u2 = *(const f32x4*)(xp + (((8 + 2 * quad) ^ s) << 2));
        f32x4 u3 = *(const f32x4*)(xp + (((9 + 2 * quad) ^ s) << 2));
        short8 a0, a1;
        #pragma unroll
        for (int j = 0; j < 4; ++j) {
            a0[j]     = (short)f2bf(u0[j]);
            a0[4 + j] = (short)f2bf(u1[j]);
            a1[j]     = (short)f2bf(u2[j]);
            a1[4 + j] = (short)f2bf(u3[j]);
        }

        #pragma unroll
        for (int mt = 0; mt < 3; ++mt)
            #pragma unroll
            for (int nt = 0; nt < 4; ++nt) {
                acc[mt][nt] = MFMA16(a0, *(const short8*)(&wf[p][mt * 8 + nt][lane][0]),     acc[mt][nt]);
                acc[mt][nt] = MFMA16(a1, *(const short8*)(&wf[p][mt * 8 + 4 + nt][lane][0]), acc[mt][nt]);
            }

        __syncthreads();
        p ^= 1;
    }

    #pragma unroll
    for (int nt = 0; nt < 4; ++nt) {
        #pragma unroll
        for (int r = 0; r < 4; ++r) {
            int m = m0 + wv * 16 + quad * 4 + r;
            int h = nt * 16 + n;
            Qo[(size_t)m * 64 + h] = f2bf(acc[0][nt][r]);
            Ko[(size_t)m * 64 + h] = f2bf(acc[1][nt][r]);
            int b = m >> 12, s2 = m & 4095;
            Vto[((size_t)(b * 80 + h)) * 4096 + s2] = f2bf(acc[2][nt][r]);
        }
    }
}

// ---------------------------------------------------------------- attention
// 128-row Q-tile, 4 waves x 32 rows (2 row-groups of 16). Double-buffered
// K/V staging (split 4 ways), one barrier per kt. Fixed-max softmax, rowsum
// via ones-column. Causal mask applied for all kt >= r0/64.
template <int SPLIT>
__device__ __forceinline__ void attn_body(
    const unsigned short* __restrict__ Q,
    const unsigned short* __restrict__ K,
    const unsigned short* __restrict__ Vt,   // [4][80][4096], row 64 = ones
    float* __restrict__ dst,
    int b, int r0, int kt0, int kt1)
{
    const int tid  = threadIdx.x;
    const int lane = tid & 63;
    const int wv   = tid >> 6;     // 0..3
    const int quad = lane >> 4;
    const int n    = lane & 15;
    const int ktmask = r0 >> 6;    // first tile that can contain key > row

    __shared__ __align__(16) short kf[2][8][64][8];            // 16 KB
    __shared__ __align__(16) short vf[2][10][64][8];           // 20 KB
    __shared__ __align__(16) unsigned short pbuf[4][32][72];   // 18 KB

    short8 qa[2][2];
    #pragma unroll
    for (int rg = 0; rg < 2; ++rg) {
        const unsigned short* qp =
            Q + (size_t)(b * 4096 + r0 + wv * 32 + rg * 16 + n) * 64 + quad * 8;
        #pragma unroll
        for (int j = 0; j < 8; ++j) {
            qa[rg][0][j] = (short)f2bf(bf2f(qp[j])      * 0.125f);
            qa[rg][1][j] = (short)f2bf(bf2f(qp[32 + j]) * 0.125f);
        }
    }

    const f32x4 zero4 = {0.f, 0.f, 0.f, 0.f};
    f32x4 oacc[2][5];
    #pragma unroll
    for (int rg = 0; rg < 2; ++rg)
        #pragma unroll
        for (int nt = 0; nt < 5; ++nt) oacc[rg][nt] = zero4;

    const unsigned short* kbase = K  + ((size_t)b * 4096 + n) * 64 + quad * 8;
    const unsigned short* vbase = Vt + ((size_t)b * 80 + n) * 4096 + quad * 8;

    auto stage = [&](int kt, int p) {
        #pragma unroll
        for (int it = 0; it < 5; ++it) {
            int f = wv + 4 * it;               // 0..19, use 0..17
            if (f < 8) {
                int c = f >> 2, nt = f & 3;
                gload16(kbase + (size_t)(kt * 64 + nt * 16) * 64 + c * 32, &kf[p][f][0][0]);
            } else if (f < 18) {
                int pnl = f - 8;               // 0..9
                int nt = pnl >> 1, c = pnl & 1;
                gload16(vbase + (size_t)nt * 16 * 4096 + kt * 64 + c * 32, &vf[p][pnl][0][0]);
            }
        }
    };

    int p = 0;
    stage(kt0, 0);
    __syncthreads();

    for (int kt = kt0; kt <= kt1; ++kt) {
        if (kt < kt1) stage(kt + 1, p ^ 1);

        short8 kfr[8];
        #pragma unroll
        for (int f = 0; f < 8; ++f)
            kfr[f] = *(const short8*)(&kf[p][f][lane][0]);

        #pragma unroll
        for (int rg = 0; rg < 2; ++rg) {
            f32x4 sacc[4] = {zero4, zero4, zero4, zero4};
            #pragma unroll
            for (int nt = 0; nt < 4; ++nt) {
                sacc[nt] = MFMA16(qa[rg][0], kfr[nt],     sacc[nt]);
                sacc[nt] = MFMA16(qa[rg][1], kfr[4 + nt], sacc[nt]);
            }
            if (kt >= ktmask) {   // tiles at/after the diagonal band
                int qg = r0 + wv * 32 + rg * 16 + quad * 4;
                #pragma unroll
                for (int nt = 0; nt < 4; ++nt)
                    #pragma unroll
                    for (int r = 0; r < 4; ++r) {
                        int key = kt * 64 + nt * 16 + n;
                        if (key > qg + r) sacc[nt][r] = -1e30f;
                    }
            }
            #pragma unroll
            for (int nt = 0; nt < 4; ++nt)
                #pragma unroll
                for (int r = 0; r < 4; ++r)
                    pbuf[wv][rg * 16 + quad * 4 + r][nt * 16 + n] = f2bf(__expf(sacc[nt][r]));
        }

        short8 vfr[10];
        #pragma unroll
        for (int pnl = 0; pnl < 10; ++pnl)
            vfr[pnl] = *(const short8*)(&vf[p][pnl][lane][0]);

        #pragma unroll
        for (int rg = 0; rg < 2; ++rg) {
            short8 pa0 = *(const short8*)(&pbuf[wv][rg * 16 + n][quad * 8]);
            short8 pa1 = *(const short8*)(&pbuf[wv][rg * 16 + n][32 + quad * 8]);
            #pragma unroll
            for (int nt = 0; nt < 5; ++nt) {
                oacc[rg][nt] = MFMA16(pa0, vfr[2 * nt],     oacc[rg][nt]);
                oacc[rg][nt] = MFMA16(pa1, vfr[2 * nt + 1], oacc[rg][nt]);
            }
        }

        __syncthreads();
        p ^= 1;
    }

    if (SPLIT) {
        // record: O[128][64] fp32 (unnormalized) + l[128] at +8192
        #pragma unroll
        for (int rg = 0; rg < 2; ++rg)
            #pragma unroll
            for (int r = 0; r < 4; ++r) {
                int row = wv * 32 + rg * 16 + quad * 4 + r;
                #pragma unroll
                for (int nt = 0; nt < 4; ++nt)
                    dst[row * 64 + nt * 16 + n] = oacc[rg][nt][r];
                if (n == 0) dst[8192 + row] = oacc[rg][4][r];
            }
    } else {
        #pragma unroll
        for (int rg = 0; rg < 2; ++rg)
            #pragma unroll
            for (int r = 0; r < 4; ++r) {
                float l   = __shfl(oacc[rg][4][r], quad * 16, 64);
                float inv = 1.f / l;
                int q = r0 + wv * 32 + rg * 16 + quad * 4 + r;
                #pragma unroll
                for (int nt = 0; nt < 4; ++nt)
                    dst[(size_t)(b * 4096 + q) * 64 + nt * 16 + n] = oacc[rg][nt][r] * inv;
            }
    }
}

// Split-K: block -> (b, qtile128, chunk of 8 kt). 4 x 144 = 576 blocks.
// nc(qt) = (qt>>2)+1; off(qt) = 2g(g+1) + (qt&3)(g+1), g = qt>>2.
__global__ __launch_bounds__(256, 2) void attn_part(
    const unsigned short* __restrict__ Q,
    const unsigned short* __restrict__ K,
    const unsigned short* __restrict__ Vt,
    float* __restrict__ Part)
{
    int id = blockIdx.x;
    int b  = id & 3;
    int t  = 143 - (id >> 2);              // heavy chunks first
    int g  = 0;
    while (2 * (g + 1) * (g + 2) <= t) ++g;
    int u  = t - 2 * g * (g + 1);
    int qt = 4 * g + u / (g + 1);
    int c  = u - (u / (g + 1)) * (g + 1);

    int r0  = qt * 128;
    int kt0 = c * 8;
    int kt1 = min(kt0 + 7, 2 * qt + 1);

    float* dst = Part + (size_t)(b * 144 + t) * 8320;
    attn_body<1>(Q, K, Vt, dst, b, r0, kt0, kt1);
}

// Monolithic fallback (ws too small): 128 blocks, whole key range.
__global__ __launch_bounds__(256, 2) void attn_mono(
    const unsigned short* __restrict__ Q,
    const unsigned short* __restrict__ K,
    const unsigned short* __restrict__ Vt,
    float* __restrict__ out)
{
    int id = blockIdx.x;
    int qt = 31 - (id >> 2);
    int b  = id & 3;
    attn_body<0>(Q, K, Vt, out, b, qt * 128, 0, 2 * qt + 1);
}

// ---------------------------------------------------------------- combine
// out = (sum_c O_c) / (sum_c l_c) over nc = (qt>>2)+1 chunks.
__global__ __launch_bounds__(256) void combine(
    const float* __restrict__ Part, float* __restrict__ out)
{
    int id = blockIdx.x;          // 128 = 4 b x 32 qt
    int b  = id & 3;
    int qt = id >> 2;
    int g  = qt >> 2;
    int nc = g + 1;
    int t0 = 2 * g * (g + 1) + (qt & 3) * (g + 1);
    const float* P0 = Part + (size_t)(b * 144 + t0) * 8320;

    __shared__ float invden[128];
    int tid = threadIdx.x;
    if (tid < 128) {
        float den = 0.f;
        for (int c = 0; c < nc; ++c) den += P0[c * 8320 + 8192 + tid];
        invden[tid] = 1.f / den;
    }
    __syncthreads();

    #pragma unroll
    for (int i = 0; i < 32; ++i) {
        int e   = tid + i * 256;      // 0..8191
        int row = e >> 6;
        float acc = 0.f;
        for (int c = 0; c < nc; ++c) acc += P0[c * 8320 + e];
        out[((size_t)b * 4096 + qt * 128 + row) * 64 + (e & 63)] = acc * invden[row];
    }
}

// ---------------------------------------------------------------- launcher
extern "C" void kernel_launch(void* const* d_in, const int* in_sizes, int n_in,
                              void* d_out, int out_size, void* d_ws, size_t ws_size,
                              hipStream_t stream) {
    const float* x  = (const float*)d_in[0];
    const float* Wq = (const float*)d_in[1];
    const float* Wk = (const float*)d_in[2];
    const float* Wv = (const float*)d_in[3];
    float* outp = (float*)d_out;
    unsigned short* ws = (unsigned short*)d_ws;

    // ws (bf16 elems): Q 1M | K 1M | Vt 4*80*4096 | Ws 192K, then fp32 partials
    unsigned short* Qw  = ws;
    unsigned short* Kw  = ws + 1048576;
    unsigned short* Vtw = ws + 2097152;            // 1310720 elems
    unsigned short* Wsp = ws + 3407872;            // 196608 elems -> end 3604480

    size_t part_off = ((size_t)3604480 * 2 + 255) & ~(size_t)255;
    size_t need     = part_off + (size_t)4 * 144 * 8320 * 4;
    float* Part = (float*)((char*)d_ws + part_off);

    transpose_w<<<dim3(1792), dim3(256), 0, stream>>>(Wq, Wk, Wv, Wsp, Vtw);
    proj_all<<<dim3(512), dim3(128), 0, stream>>>(x, Wsp, Qw, Kw, Vtw);

    if (ws_size >= need) {
        attn_part<<<dim3(576), dim3(256), 0, stream>>>(Qw, Kw, Vtw, Part);
        combine<<<dim3(128), dim3(256), 0, stream>>>(Part, outp);
    } else {
        attn_mono<<<dim3(128), dim3(256), 0, stream>>>(Qw, Kw, Vtw, outp);
    }
}

// Round 11
// 156.769 us; speedup vs baseline: 1.3795x; 1.3795x over previous
//
#include <hip/hip_runtime.h>

// SelfAttention: B=4, S=4096, E=1024, H=64, single head, causal, p=0.
// I/O fp32, internals bf16 MFMA.
// Round 11: combine rewritten for load parallelism (R10's combine was a
// serial-latency chain: 144 dependent-ish loads/thread at 1 wave/SIMD).
// Now 512 blocks x 32-row slices, c-loop outermost with 8 independent
// accumulators -> chain length nc (<=8). Everything else identical to R10.

using short8 = __attribute__((ext_vector_type(8))) short;
using f32x4  = __attribute__((ext_vector_type(4))) float;

#define MFMA16(A, B, C) __builtin_amdgcn_mfma_f32_16x16x32_bf16((A), (B), (C), 0, 0, 0)

typedef const __attribute__((address_space(1))) void* gas_ptr;
typedef __attribute__((address_space(3))) void*       las_ptr;

__device__ __forceinline__ void gload16(const void* g, void* l) {
    // async global->LDS, 16B/lane, LDS dst = base + lane*16 (wave-uniform base)
    __builtin_amdgcn_global_load_lds((gas_ptr)g, (las_ptr)l, 16, 0, 0);
}

__device__ __forceinline__ unsigned short f2bf(float f) {
    unsigned u = __builtin_bit_cast(unsigned, f);
    u += 0x7fffu + ((u >> 16) & 1u);   // RNE
    return (unsigned short)(u >> 16);
}
__device__ __forceinline__ float bf2f(unsigned short u) {
    unsigned v = ((unsigned)u) << 16;
    return __builtin_bit_cast(float, v);
}

// ------------------------------------------------- W frag-order pack + Vt pad
__global__ __launch_bounds__(256) void transpose_w(
    const float* __restrict__ Wq,
    const float* __restrict__ Wk,
    const float* __restrict__ Wv,
    unsigned short* __restrict__ Ws,
    unsigned short* __restrict__ Vt)
{
    int o = blockIdx.x * 256 + threadIdx.x;   // 196608 + 262144 total
    if (o < 196608) {
        int j    = o & 7;
        int l    = (o >> 3) & 63;
        int g    = (o >> 9) & 7;
        int rem  = o >> 12;        // sk*3 + mt
        int mt   = rem % 3;
        int sk   = rem / 3;
        int c    = g >> 2, nt = g & 3;
        int quad = l >> 4, n  = l & 15;
        int e    = sk * 64 + c * 32 + quad * 8 + j;
        int h    = nt * 16 + n;
        const float* W = (mt == 0) ? Wq : (mt == 1) ? Wk : Wv;
        Ws[o] = f2bf(W[e * 64 + h]);
    } else {
        int jj  = o - 196608;                 // 4 b x 16 rows x 4096
        int b   = jj >> 16;
        int rem = jj & 65535;
        int h   = 64 + (rem >> 12);
        int s   = rem & 4095;
        Vt[((size_t)(b * 80 + h)) * 4096 + s] = (h == 64) ? 0x3F80 : 0;
    }
}

// ---------------------------------------------------------------- projection
// (R9 structure, unchanged)
__global__ __launch_bounds__(128, 2) void proj_all(
    const float* __restrict__ x,             // [16384][1024] fp32
    const unsigned short* __restrict__ Ws,   // [16][3][8][64][8] bf16 frag-order
    unsigned short* __restrict__ Qo,         // [16384][64] bf16
    unsigned short* __restrict__ Ko,         // [16384][64] bf16
    unsigned short* __restrict__ Vto)        // [4][80][4096] bf16 (V^T, padded)
{
    const int m0   = blockIdx.x * 32;
    const int tid  = threadIdx.x;
    const int lane = tid & 63;
    const int wv   = tid >> 6;     // 0..1
    const int quad = lane >> 4;
    const int n    = lane & 15;

    __shared__ __align__(16) float xs[2][8][64][4];   // 16 KB
    __shared__ __align__(16) short wf[2][24][64][8];  // 48 KB

    const f32x4 zero4 = {0.f, 0.f, 0.f, 0.f};
    f32x4 acc[3][4];
    #pragma unroll
    for (int mt = 0; mt < 3; ++mt)
        #pragma unroll
        for (int nt = 0; nt < 4; ++nt) acc[mt][nt] = zero4;

    auto stage = [&](int k0, int p) {
        #pragma unroll
        for (int it = 0; it < 4; ++it) {
            int i     = wv + 2 * it;                 // 0..7
            int Rl    = 4 * i + (lane >> 4);         // local row 0..31
            int chunk = (lane & 15) ^ ((Rl & 3) << 2);
            gload16(x + (size_t)(m0 + Rl) * 1024 + k0 + chunk * 4, &xs[p][i][0][0]);
        }
        int sk = k0 >> 6;
        #pragma unroll
        for (int it = 0; it < 12; ++it) {
            int f = wv + 2 * it;                     // 0..23
            gload16(Ws + (((size_t)sk * 24 + f) << 9) + lane * 8, &wf[p][f][0][0]);
        }
    };

    int p = 0;
    stage(0, 0);
    __syncthreads();

    for (int k0 = 0; k0 < 1024; k0 += 64) {
        if (k0 < 960) stage(k0 + 64, p ^ 1);   // prefetch (drained at barrier)

        int sub = n & 3, s = sub << 2;
        const float* xp = &xs[p][wv * 4 + (n >> 2)][0][0] + sub * 64;
        f32x4 u0 = *(const f32x4*)(xp + (((2 * quad)     ^ s) << 2));
        f32x4 u1 = *(const f32x4*)(xp + (((2 * quad + 1) ^ s) << 2));
        f32x4 u2 = *(const f32x4*)(xp + (((8 + 2 * quad) ^ s) << 2));
        f32x4 u3 = *(const f32x4*)(xp + (((9 + 2 * quad) ^ s) << 2));
        short8 a0, a1;
        #pragma unroll
        for (int j = 0; j < 4; ++j) {
            a0[j]     = (short)f2bf(u0[j]);
            a0[4 + j] = (short)f2bf(u1[j]);
            a1[j]     = (short)f2bf(u2[j]);
            a1[4 + j] = (short)f2bf(u3[j]);
        }

        #pragma unroll
        for (int mt = 0; mt < 3; ++mt)
            #pragma unroll
            for (int nt = 0; nt < 4; ++nt) {
                acc[mt][nt] = MFMA16(a0, *(const short8*)(&wf[p][mt * 8 + nt][lane][0]),     acc[mt][nt]);
                acc[mt][nt] = MFMA16(a1, *(const short8*)(&wf[p][mt * 8 + 4 + nt][lane][0]), acc[mt][nt]);
            }

        __syncthreads();
        p ^= 1;
    }

    #pragma unroll
    for (int nt = 0; nt < 4; ++nt) {
        #pragma unroll
        for (int r = 0; r < 4; ++r) {
            int m = m0 + wv * 16 + quad * 4 + r;
            int h = nt * 16 + n;
            Qo[(size_t)m * 64 + h] = f2bf(acc[0][nt][r]);
            Ko[(size_t)m * 64 + h] = f2bf(acc[1][nt][r]);
            int b = m >> 12, s2 = m & 4095;
            Vto[((size_t)(b * 80 + h)) * 4096 + s2] = f2bf(acc[2][nt][r]);
        }
    }
}

// ---------------------------------------------------------------- attention
// (R10 structure, unchanged) 128-row Q-tile, 4 waves x 32 rows.
template <int SPLIT>
__device__ __forceinline__ void attn_body(
    const unsigned short* __restrict__ Q,
    const unsigned short* __restrict__ K,
    const unsigned short* __restrict__ Vt,   // [4][80][4096], row 64 = ones
    float* __restrict__ dst,
    int b, int r0, int kt0, int kt1)
{
    const int tid  = threadIdx.x;
    const int lane = tid & 63;
    const int wv   = tid >> 6;     // 0..3
    const int quad = lane >> 4;
    const int n    = lane & 15;
    const int ktmask = r0 >> 6;

    __shared__ __align__(16) short kf[2][8][64][8];            // 16 KB
    __shared__ __align__(16) short vf[2][10][64][8];           // 20 KB
    __shared__ __align__(16) unsigned short pbuf[4][32][72];   // 18 KB

    short8 qa[2][2];
    #pragma unroll
    for (int rg = 0; rg < 2; ++rg) {
        const unsigned short* qp =
            Q + (size_t)(b * 4096 + r0 + wv * 32 + rg * 16 + n) * 64 + quad * 8;
        #pragma unroll
        for (int j = 0; j < 8; ++j) {
            qa[rg][0][j] = (short)f2bf(bf2f(qp[j])      * 0.125f);
            qa[rg][1][j] = (short)f2bf(bf2f(qp[32 + j]) * 0.125f);
        }
    }

    const f32x4 zero4 = {0.f, 0.f, 0.f, 0.f};
    f32x4 oacc[2][5];
    #pragma unroll
    for (int rg = 0; rg < 2; ++rg)
        #pragma unroll
        for (int nt = 0; nt < 5; ++nt) oacc[rg][nt] = zero4;

    const unsigned short* kbase = K  + ((size_t)b * 4096 + n) * 64 + quad * 8;
    const unsigned short* vbase = Vt + ((size_t)b * 80 + n) * 4096 + quad * 8;

    auto stage = [&](int kt, int p) {
        #pragma unroll
        for (int it = 0; it < 5; ++it) {
            int f = wv + 4 * it;               // 0..19, use 0..17
            if (f < 8) {
                int c = f >> 2, nt = f & 3;
                gload16(kbase + (size_t)(kt * 64 + nt * 16) * 64 + c * 32, &kf[p][f][0][0]);
            } else if (f < 18) {
                int pnl = f - 8;               // 0..9
                int nt = pnl >> 1, c = pnl & 1;
                gload16(vbase + (size_t)nt * 16 * 4096 + kt * 64 + c * 32, &vf[p][pnl][0][0]);
            }
        }
    };

    int p = 0;
    stage(kt0, 0);
    __syncthreads();

    for (int kt = kt0; kt <= kt1; ++kt) {
        if (kt < kt1) stage(kt + 1, p ^ 1);

        short8 kfr[8];
        #pragma unroll
        for (int f = 0; f < 8; ++f)
            kfr[f] = *(const short8*)(&kf[p][f][lane][0]);

        #pragma unroll
        for (int rg = 0; rg < 2; ++rg) {
            f32x4 sacc[4] = {zero4, zero4, zero4, zero4};
            #pragma unroll
            for (int nt = 0; nt < 4; ++nt) {
                sacc[nt] = MFMA16(qa[rg][0], kfr[nt],     sacc[nt]);
                sacc[nt] = MFMA16(qa[rg][1], kfr[4 + nt], sacc[nt]);
            }
            if (kt >= ktmask) {
                int qg = r0 + wv * 32 + rg * 16 + quad * 4;
                #pragma unroll
                for (int nt = 0; nt < 4; ++nt)
                    #pragma unroll
                    for (int r = 0; r < 4; ++r) {
                        int key = kt * 64 + nt * 16 + n;
                        if (key > qg + r) sacc[nt][r] = -1e30f;
                    }
            }
            #pragma unroll
            for (int nt = 0; nt < 4; ++nt)
                #pragma unroll
                for (int r = 0; r < 4; ++r)
                    pbuf[wv][rg * 16 + quad * 4 + r][nt * 16 + n] = f2bf(__expf(sacc[nt][r]));
        }

        short8 vfr[10];
        #pragma unroll
        for (int pnl = 0; pnl < 10; ++pnl)
            vfr[pnl] = *(const short8*)(&vf[p][pnl][lane][0]);

        #pragma unroll
        for (int rg = 0; rg < 2; ++rg) {
            short8 pa0 = *(const short8*)(&pbuf[wv][rg * 16 + n][quad * 8]);
            short8 pa1 = *(const short8*)(&pbuf[wv][rg * 16 + n][32 + quad * 8]);
            #pragma unroll
            for (int nt = 0; nt < 5; ++nt) {
                oacc[rg][nt] = MFMA16(pa0, vfr[2 * nt],     oacc[rg][nt]);
                oacc[rg][nt] = MFMA16(pa1, vfr[2 * nt + 1], oacc[rg][nt]);
            }
        }

        __syncthreads();
        p ^= 1;
    }

    if (SPLIT) {
        // record: O[128][64] fp32 (unnormalized) + l[128] at +8192
        #pragma unroll
        for (int rg = 0; rg < 2; ++rg)
            #pragma unroll
            for (int r = 0; r < 4; ++r) {
                int row = wv * 32 + rg * 16 + quad * 4 + r;
                #pragma unroll
                for (int nt = 0; nt < 4; ++nt)
                    dst[row * 64 + nt * 16 + n] = oacc[rg][nt][r];
                if (n == 0) dst[8192 + row] = oacc[rg][4][r];
            }
    } else {
        #pragma unroll
        for (int rg = 0; rg < 2; ++rg)
            #pragma unroll
            for (int r = 0; r < 4; ++r) {
                float l   = __shfl(oacc[rg][4][r], quad * 16, 64);
                float inv = 1.f / l;
                int q = r0 + wv * 32 + rg * 16 + quad * 4 + r;
                #pragma unroll
                for (int nt = 0; nt < 4; ++nt)
                    dst[(size_t)(b * 4096 + q) * 64 + nt * 16 + n] = oacc[rg][nt][r] * inv;
            }
    }
}

// Split-K: block -> (b, qtile128, chunk of 8 kt). 4 x 144 = 576 blocks.
__global__ __launch_bounds__(256, 2) void attn_part(
    const unsigned short* __restrict__ Q,
    const unsigned short* __restrict__ K,
    const unsigned short* __restrict__ Vt,
    float* __restrict__ Part)
{
    int id = blockIdx.x;
    int b  = id & 3;
    int t  = 143 - (id >> 2);              // heavy chunks first
    int g  = 0;
    while (2 * (g + 1) * (g + 2) <= t) ++g;
    int u  = t - 2 * g * (g + 1);
    int qt = 4 * g + u / (g + 1);
    int c  = u - (u / (g + 1)) * (g + 1);

    int r0  = qt * 128;
    int kt0 = c * 8;
    int kt1 = min(kt0 + 7, 2 * qt + 1);

    float* dst = Part + (size_t)(b * 144 + t) * 8320;
    attn_body<1>(Q, K, Vt, dst, b, r0, kt0, kt1);
}

// Monolithic fallback (ws too small).
__global__ __launch_bounds__(256, 2) void attn_mono(
    const unsigned short* __restrict__ Q,
    const unsigned short* __restrict__ K,
    const unsigned short* __restrict__ Vt,
    float* __restrict__ out)
{
    int id = blockIdx.x;
    int qt = 31 - (id >> 2);
    int b  = id & 3;
    attn_body<0>(Q, K, Vt, out, b, qt * 128, 0, 2 * qt + 1);
}

// ---------------------------------------------------------------- combine
// 512 blocks = (4 b x 32 qt) x 4 slices of 32 rows. c-loop OUTERMOST with 8
// independent accumulators/thread: serial chain = nc (<=8) load latencies.
__global__ __launch_bounds__(256) void combine(
    const float* __restrict__ Part, float* __restrict__ out)
{
    int id    = blockIdx.x;
    int slice = id & 3;
    int bq    = id >> 2;
    int b     = bq & 3;
    int qt    = bq >> 2;
    int g     = qt >> 2;
    int nc    = g + 1;
    int t0    = 2 * g * (g + 1) + (qt & 3) * (g + 1);
    const float* P0 = Part + (size_t)(b * 144 + t0) * 8320;

    int tid = threadIdx.x;

    // denominators for this slice's 32 rows (parallel across c via 8 regs)
    __shared__ float invden[32];
    if (tid < 32) {
        float d[8] = {0, 0, 0, 0, 0, 0, 0, 0};
        #pragma unroll 8
        for (int c = 0; c < 8; ++c)
            if (c < nc) d[c] = P0[c * 8320 + 8192 + slice * 32 + tid];
        invden[tid] = 1.f / (((d[0] + d[1]) + (d[2] + d[3])) +
                             ((d[4] + d[5]) + (d[6] + d[7])));
    }

    // 2048 elements: 8 per thread, accumulate with c outermost
    float acc[8] = {0, 0, 0, 0, 0, 0, 0, 0};
    const float* Pe = P0 + slice * 2048 + tid;
    for (int c = 0; c < nc; ++c) {
        const float* Pc = Pe + (size_t)c * 8320;
        #pragma unroll
        for (int j = 0; j < 8; ++j)
            acc[j] += Pc[j * 256];
    }

    __syncthreads();
    #pragma unroll
    for (int j = 0; j < 8; ++j) {
        int e   = slice * 2048 + j * 256 + tid;
        int row = (e >> 6) & 31;
        out[((size_t)b * 4096 + qt * 128 + slice * 32) * 64 + (size_t)(j * 256 + tid)]
            = acc[j] * invden[row];
    }
}

// ---------------------------------------------------------------- launcher
extern "C" void kernel_launch(void* const* d_in, const int* in_sizes, int n_in,
                              void* d_out, int out_size, void* d_ws, size_t ws_size,
                              hipStream_t stream) {
    const float* x  = (const float*)d_in[0];
    const float* Wq = (const float*)d_in[1];
    const float* Wk = (const float*)d_in[2];
    const float* Wv = (const float*)d_in[3];
    float* outp = (float*)d_out;
    unsigned short* ws = (unsigned short*)d_ws;

    // ws (bf16 elems): Q 1M | K 1M | Vt 4*80*4096 | Ws 192K, then fp32 partials
    unsigned short* Qw  = ws;
    unsigned short* Kw  = ws + 1048576;
    unsigned short* Vtw = ws + 2097152;            // 1310720 elems
    unsigned short* Wsp = ws + 3407872;            // 196608 elems -> end 3604480

    size_t part_off = ((size_t)3604480 * 2 + 255) & ~(size_t)255;
    size_t need     = part_off + (size_t)4 * 144 * 8320 * 4;
    float* Part = (float*)((char*)d_ws + part_off);

    transpose_w<<<dim3(1792), dim3(256), 0, stream>>>(Wq, Wk, Wv, Wsp, Vtw);
    proj_all<<<dim3(512), dim3(128), 0, stream>>>(x, Wsp, Qw, Kw, Vtw);

    if (ws_size >= need) {
        attn_part<<<dim3(576), dim3(256), 0, stream>>>(Qw, Kw, Vtw, Part);
        combine<<<dim3(512), dim3(256), 0, stream>>>(Part, outp);
    } else {
        attn_mono<<<dim3(128), dim3(256), 0, stream>>>(Qw, Kw, Vtw, outp);
    }
}